// Round 5
// baseline (145.878 us; speedup 1.0000x reference)
//
#include <hip/hip_runtime.h>
#include <math.h>

// cSE channel self-attention, bf16-MFMA hi/lo, double-buffered, NT-store PV.
// x: [N=4][C=128][S=110592] f32.  out: same shape f32.
// energy = Q Q^T; attn_ij = exp(rowmin - e_ij)/sum (== reference softmax(max-e));
// out = attn @ Q.
//
// L3 strategy: x (226.5 MB) + partials (16.8 MB) ~ fit the 256 MB Infinity
// Cache. gram reads x with NORMAL loads (allocate -> resident for PV). PV
// reads x with NON-TEMPORAL loads (read-once) and writes out with
// NON-TEMPORAL stores (no allocation -> does not evict x). attn stays bf16-hi
// only: rows sum to 1 => dropped-lo error <= 2^-9 * max|q| ~ 0.011.

static constexpr int CN = 128;
static constexpr int SN = 110592;      // 48^3
static constexpr int NB = 4;

static constexpr int GB = 64;          // gram K-slices per batch (256 blocks = 1/CU)
static constexpr int GSL = SN / GB;    // 1728
static constexpr int GCH = GSL / 64;   // 27 chunks of K=64

static constexpr int PB = 432;         // pv s-blocks per batch (256 s each)
static constexpr int PCH = 4;          // chunks of 64 s per block

typedef float  f32x4  __attribute__((ext_vector_type(4)));
typedef short  bf16x8 __attribute__((ext_vector_type(8)));
typedef unsigned short u16x8 __attribute__((ext_vector_type(8)));
typedef unsigned short u16x4 __attribute__((ext_vector_type(4)));

// f32 -> (hi bf16, lo bf16) round-to-nearest-even, packed lo<<16|hi
__device__ __forceinline__ unsigned int splitpack(float v) {
    unsigned int u = __float_as_uint(v);
    unsigned int h = (u + 0x7fffu + ((u >> 16) & 1u)) >> 16;
    float lf = v - __uint_as_float(h << 16);
    unsigned int ul = __float_as_uint(lf);
    unsigned int l = (ul + 0x7fffu + ((ul >> 16) & 1u)) >> 16;
    return (l << 16) | (h & 0xffffu);
}
__device__ __forceinline__ unsigned short f2bh(float v) {
    unsigned int u = __float_as_uint(v);
    return (unsigned short)((u + 0x7fffu + ((u >> 16) & 1u)) >> 16);
}

// swizzled LDS fragment read: 16 B along k at given row
__device__ __forceinline__ bf16x8 ldsfrag(const unsigned short* base, int row, int kbyte, int pitchB) {
    const char* p = reinterpret_cast<const char*>(base) + row * pitchB + (kbyte ^ ((row & 7) << 4));
    return *reinterpret_cast<const bf16x8*>(p);
}
__device__ __forceinline__ f32x4 mm(bf16x8 a, bf16x8 b, f32x4 c) {
    return __builtin_amdgcn_mfma_f32_16x16x32_bf16(a, b, c, 0, 0, 0);
}

// ---------------- K1: Gram via MFMA, hi/lo split, double-buffered ----------------
// grid (GB, NB), block 512 (8 waves). Each block: K-slice of 1728, 27 chunks of 64.
// LDS: 2 x ([128 c][64 k] bf16 hi + lo), pitch 128B, XOR-swizzled.  64 KB total.
template <bool ATOMIC>
__global__ __launch_bounds__(512, 2) void gram_mfma(const float* __restrict__ x,
                                                    float* __restrict__ dst) {
    __shared__ __align__(16) unsigned short lh[2][CN * 64];
    __shared__ __align__(16) unsigned short ll[2][CN * 64];
    const int bx = blockIdx.x, n = blockIdx.y;
    const int tid = threadIdx.x;
    const int lane = tid & 63;
    const int w = tid >> 6;                // 0..7
    const int wr = w >> 2, wc = w & 3;     // wave grid 2x4
    const int ra = lane & 15, kg = lane >> 4;

    // staging mapping: thread -> (channel c, 16 consecutive k)
    const int c  = tid >> 2;               // 0..127
    const int ks = (tid & 3) << 4;         // 0,16,32,48
    const float* gq = x + (size_t)n * CN * SN + (size_t)c * SN + bx * GSL;

    f32x4 acc[4][2];
#pragma unroll
    for (int a = 0; a < 4; ++a)
#pragma unroll
        for (int b = 0; b < 2; ++b) acc[a][b] = (f32x4){0.f, 0.f, 0.f, 0.f};

    float4 st[4];
    auto load_chunk = [&](int t) {
        const float4* p = reinterpret_cast<const float4*>(gq + t * 64 + ks);
        st[0] = p[0]; st[1] = p[1]; st[2] = p[2]; st[3] = p[3];
    };

    auto stage = [&](int buf) {
        u16x8 ha, hb, la, lb;
        unsigned int p;
#define CV8(hv, lv, i, val) { p = splitpack(val); hv[i] = (unsigned short)(p & 0xffffu); lv[i] = (unsigned short)(p >> 16); }
        CV8(ha, la, 0, st[0].x) CV8(ha, la, 1, st[0].y) CV8(ha, la, 2, st[0].z) CV8(ha, la, 3, st[0].w)
        CV8(ha, la, 4, st[1].x) CV8(ha, la, 5, st[1].y) CV8(ha, la, 6, st[1].z) CV8(ha, la, 7, st[1].w)
        CV8(hb, lb, 0, st[2].x) CV8(hb, lb, 1, st[2].y) CV8(hb, lb, 2, st[2].z) CV8(hb, lb, 3, st[2].w)
        CV8(hb, lb, 4, st[3].x) CV8(hb, lb, 5, st[3].y) CV8(hb, lb, 6, st[3].z) CV8(hb, lb, 7, st[3].w)
#undef CV8
        char* ph = reinterpret_cast<char*>(lh[buf]) + c * 128;
        char* pl = reinterpret_cast<char*>(ll[buf]) + c * 128;
        const int sw = (c & 7) << 4;
        const int k2 = ks * 2;
        *reinterpret_cast<u16x8*>(ph + (k2 ^ sw))        = ha;
        *reinterpret_cast<u16x8*>(ph + ((k2 + 16) ^ sw)) = hb;
        *reinterpret_cast<u16x8*>(pl + (k2 ^ sw))        = la;
        *reinterpret_cast<u16x8*>(pl + ((k2 + 16) ^ sw)) = lb;
    };

    auto compute = [&](int buf) {
        const unsigned short* LH = lh[buf];
        const unsigned short* LL = ll[buf];
#pragma unroll
        for (int kk = 0; kk < 2; ++kk) {
            const int kb = kk * 64 + (kg << 4);
            bf16x8 ah[4], al[4], bh[2], bl[2];
#pragma unroll
            for (int it = 0; it < 4; ++it) {
                const int row = wr * 64 + it * 16 + ra;
                ah[it] = ldsfrag(LH, row, kb, 128);
                al[it] = ldsfrag(LL, row, kb, 128);
            }
#pragma unroll
            for (int jt = 0; jt < 2; ++jt) {
                const int row = wc * 32 + jt * 16 + ra;
                bh[jt] = ldsfrag(LH, row, kb, 128);
                bl[jt] = ldsfrag(LL, row, kb, 128);
            }
#pragma unroll
            for (int it = 0; it < 4; ++it)
#pragma unroll
                for (int jt = 0; jt < 2; ++jt) {
                    acc[it][jt] = mm(ah[it], bh[jt], acc[it][jt]);
                    acc[it][jt] = mm(ah[it], bl[jt], acc[it][jt]);
                    acc[it][jt] = mm(al[it], bh[jt], acc[it][jt]);
                }
        }
    };

    load_chunk(0);
    for (int t = 0; t < GCH; ++t) {
        stage(t & 1);
        if (t < GCH - 1) load_chunk(t + 1);   // prefetch overlaps MFMA
        __syncthreads();                      // single barrier per chunk (dbuf)
        compute(t & 1);
    }

    // epilogue: C/D map row=(lane>>4)*4+q, col=lane&15
    const int q4 = kg << 2;
    if (!ATOMIC) {
        float* P = dst + (size_t)(n * GB + bx) * (CN * CN);
#pragma unroll
        for (int it = 0; it < 4; ++it)
#pragma unroll
            for (int jt = 0; jt < 2; ++jt)
#pragma unroll
                for (int q = 0; q < 4; ++q)
                    P[(wr * 64 + it * 16 + q4 + q) * CN + wc * 32 + jt * 16 + ra] = acc[it][jt][q];
    } else {
        float* E = dst + (size_t)n * CN * CN;
#pragma unroll
        for (int it = 0; it < 4; ++it)
#pragma unroll
            for (int jt = 0; jt < 2; ++jt)
#pragma unroll
                for (int q = 0; q < 4; ++q)
                    atomicAdd(&E[(wr * 64 + it * 16 + q4 + q) * CN + wc * 32 + jt * 16 + ra], acc[it][jt][q]);
    }
}

// ---------------- K2: fused reduce + softmin -> bf16-hi attention ----------------
// grid (CN, NB), block 64 (one wave per row). Deterministic fixed-order k sum.
template <bool REDUCE>
__global__ void finish_kernel(const float* __restrict__ src,
                              unsigned short* __restrict__ att_h) {
    const int i = blockIdx.x, n = blockIdx.y, l = threadIdx.x;
    float e0, e1;
    if (REDUCE) {
        const float* p = src + (size_t)n * GB * (CN * CN) + i * CN;
        e0 = 0.f; e1 = 0.f;
#pragma unroll 8
        for (int k = 0; k < GB; ++k) {
            e0 += p[(size_t)k * (CN * CN) + l];
            e1 += p[(size_t)k * (CN * CN) + l + 64];
        }
    } else {
        const float* E = src + ((size_t)n * CN + i) * CN;
        e0 = E[l]; e1 = E[l + 64];
    }
    float m = fminf(e0, e1);
#pragma unroll
    for (int off = 32; off > 0; off >>= 1) m = fminf(m, __shfl_xor(m, off));
    const float p0 = expf(m - e0);
    const float p1 = expf(m - e1);
    float s = p0 + p1;
#pragma unroll
    for (int off = 32; off > 0; off >>= 1) s += __shfl_xor(s, off);
    const float inv = 1.f / s;
    const size_t o = ((size_t)n * CN + i) * CN;
    att_h[o + l]      = f2bh(p0 * inv);
    att_h[o + l + 64] = f2bh(p1 * inv);
}

// ---------------- K3: out = attn @ Q via MFMA, double-buffered, NT I/O ----------------
// grid (PB, NB), block 512. Per block: 256 s (4 chunks of 64).
// A = attn-hi in registers (rows sum to 1 -> lo-term bounded by 2^-9*max|q|).
// B = q-hi only. x loads NT (read-once), out stores NT (protect x in L3).
// LDS: 2 x [64 s][128 j] bf16 hi, pitch 256B, XOR-swizzled.  32 KB.
__global__ __launch_bounds__(512, 4) void pv_mfma(const float* __restrict__ x,
                                                  const unsigned short* __restrict__ att_h,
                                                  float* __restrict__ out) {
    __shared__ __align__(16) unsigned short qh[2][64 * CN];
    const int bx = blockIdx.x, n = blockIdx.y;
    const int tid = threadIdx.x;
    const int lane = tid & 63;
    const int w = tid >> 6;                 // wave -> i-tile (rows w*16..w*16+15)
    const int ra = lane & 15, kg = lane >> 4;

    // A-fragments from global (attn L2-resident across blocks)
    bf16x8 a_h[4];
    {
        const size_t rowoff = ((size_t)n * CN + w * 16 + ra) * CN + kg * 8;
        const unsigned short* Ah = att_h + rowoff;
#pragma unroll
        for (int kk = 0; kk < 4; ++kk)
            a_h[kk] = *reinterpret_cast<const bf16x8*>(Ah + kk * 32);
    }

    // staging mapping: thread -> 4x4 micro-block (j0..j0+3, s0..s0+3)
    const int j0 = (tid >> 4) * 4;          // 0..124
    const int s0 = (tid & 15) * 4;          // 0..60
    const float* gx = x + (size_t)n * CN * SN;
    const int sbase = bx * (PCH * 64);

    f32x4 st[4];
    auto load_chunk = [&](int sb) {
#pragma unroll
        for (int r = 0; r < 4; ++r)
            st[r] = __builtin_nontemporal_load(
                reinterpret_cast<const f32x4*>(gx + (size_t)(j0 + r) * SN + sb + s0));
    };

    auto stage = [&](int buf) {
        char* base = reinterpret_cast<char*>(qh[buf]);
#pragma unroll
        for (int r = 0; r < 4; ++r) {       // r = local s offset (compile-time)
            u16x4 hv;
            hv[0] = f2bh(st[0][r]);
            hv[1] = f2bh(st[1][r]);
            hv[2] = f2bh(st[2][r]);
            hv[3] = f2bh(st[3][r]);
            const int s = s0 + r;
            const int off = s * 256 + ((j0 * 2) ^ ((s & 7) << 4));
            *reinterpret_cast<u16x4*>(base + off) = hv;
        }
    };

    auto compute = [&](int buf, int sb) {
        const unsigned short* Q = qh[buf];
#pragma unroll
        for (int stile = 0; stile < 4; ++stile) {
            f32x4 acc = (f32x4){0.f, 0.f, 0.f, 0.f};
            const int srow = stile * 16 + ra;
#pragma unroll
            for (int kk = 0; kk < 4; ++kk) {
                const int kb = kk * 64 + (kg << 4);
                bf16x8 bh = ldsfrag(Q, srow, kb, 256);
                acc = mm(a_h[kk], bh, acc);
            }
            float* o = out + ((size_t)n * CN + w * 16 + (kg << 2)) * SN + sb + stile * 16 + ra;
#pragma unroll
            for (int q = 0; q < 4; ++q)
                __builtin_nontemporal_store(acc[q], o + (size_t)q * SN);
        }
    };

    load_chunk(sbase);
    for (int t = 0; t < PCH; ++t) {
        stage(t & 1);
        if (t < PCH - 1) load_chunk(sbase + (t + 1) * 64);
        __syncthreads();
        compute(t & 1, sbase + t * 64);
    }
}

extern "C" void kernel_launch(void* const* d_in, const int* in_sizes, int n_in,
                              void* d_out, int out_size, void* d_ws, size_t ws_size,
                              hipStream_t stream) {
    (void)in_sizes; (void)n_in; (void)out_size;
    const float* x = (const float*)d_in[0];
    float* out = (float*)d_out;

    // ws: [energy 256KB][att_h 128KB][partials 16.8MB]
    float* energy = (float*)d_ws;
    unsigned short* att_h = (unsigned short*)(energy + (size_t)NB * CN * CN);
    float* part = (float*)(att_h + (size_t)NB * CN * CN);
    const size_t need =
        (size_t)NB * CN * CN * sizeof(float) +
        (size_t)NB * CN * CN * sizeof(unsigned short) +
        (size_t)NB * GB * CN * CN * sizeof(float);

    if (ws_size >= need) {
        gram_mfma<false><<<dim3(GB, NB), 512, 0, stream>>>(x, part);
        finish_kernel<true><<<dim3(CN, NB), 64, 0, stream>>>(part, att_h);
    } else {
        hipMemsetAsync(energy, 0, (size_t)NB * CN * CN * sizeof(float), stream);
        gram_mfma<true><<<dim3(GB, NB), 512, 0, stream>>>(x, energy);
        finish_kernel<false><<<dim3(CN, NB), 64, 0, stream>>>(energy, att_h);
    }
    pv_mfma<<<dim3(PB, NB), 512, 0, stream>>>(x, att_h, out);
}

// Round 6
// 138.404 us; speedup vs baseline: 1.0540x; 1.0540x over previous
//
#include <hip/hip_runtime.h>
#include <math.h>

// cSE channel self-attention, bf16-MFMA hi/lo, double-buffered.
// x: [N=4][C=128][S=110592] f32.  out: same shape f32.
// energy = Q Q^T; attn_ij = exp(rowmin - e_ij)/sum (== reference softmax(max-e));
// out = attn @ Q.
//
// Round-6 A/B: PV x loads NORMAL (L3 hits after gram), out stores NT
// (test Infinity-Cache allocation bypass), attn bf16-hi only (validated:
// rows sum to 1 => dropped-lo error <= 2^-9 * max|q| ~ 0.011).

static constexpr int CN = 128;
static constexpr int SN = 110592;      // 48^3
static constexpr int NB = 4;

static constexpr int GB = 64;          // gram K-slices per batch (256 blocks = 1/CU)
static constexpr int GSL = SN / GB;    // 1728
static constexpr int GCH = GSL / 64;   // 27 chunks of K=64

static constexpr int PB = 432;         // pv s-blocks per batch (256 s each)
static constexpr int PCH = 4;          // chunks of 64 s per block

typedef float  f32x4  __attribute__((ext_vector_type(4)));
typedef short  bf16x8 __attribute__((ext_vector_type(8)));
typedef unsigned short u16x8 __attribute__((ext_vector_type(8)));
typedef unsigned short u16x4 __attribute__((ext_vector_type(4)));

// f32 -> (hi bf16, lo bf16) round-to-nearest-even, packed lo<<16|hi
__device__ __forceinline__ unsigned int splitpack(float v) {
    unsigned int u = __float_as_uint(v);
    unsigned int h = (u + 0x7fffu + ((u >> 16) & 1u)) >> 16;
    float lf = v - __uint_as_float(h << 16);
    unsigned int ul = __float_as_uint(lf);
    unsigned int l = (ul + 0x7fffu + ((ul >> 16) & 1u)) >> 16;
    return (l << 16) | (h & 0xffffu);
}
__device__ __forceinline__ unsigned short f2bh(float v) {
    unsigned int u = __float_as_uint(v);
    return (unsigned short)((u + 0x7fffu + ((u >> 16) & 1u)) >> 16);
}

// swizzled LDS fragment read: 16 B along k at given row
__device__ __forceinline__ bf16x8 ldsfrag(const unsigned short* base, int row, int kbyte, int pitchB) {
    const char* p = reinterpret_cast<const char*>(base) + row * pitchB + (kbyte ^ ((row & 7) << 4));
    return *reinterpret_cast<const bf16x8*>(p);
}
__device__ __forceinline__ f32x4 mm(bf16x8 a, bf16x8 b, f32x4 c) {
    return __builtin_amdgcn_mfma_f32_16x16x32_bf16(a, b, c, 0, 0, 0);
}

// ---------------- K1: Gram via MFMA, hi/lo split, double-buffered ----------------
// grid (GB, NB), block 512 (8 waves). Each block: K-slice of 1728, 27 chunks of 64.
// LDS: 2 x ([128 c][64 k] bf16 hi + lo), pitch 128B, XOR-swizzled.  64 KB total.
template <bool ATOMIC>
__global__ __launch_bounds__(512, 2) void gram_mfma(const float* __restrict__ x,
                                                    float* __restrict__ dst) {
    __shared__ __align__(16) unsigned short lh[2][CN * 64];
    __shared__ __align__(16) unsigned short ll[2][CN * 64];
    const int bx = blockIdx.x, n = blockIdx.y;
    const int tid = threadIdx.x;
    const int lane = tid & 63;
    const int w = tid >> 6;                // 0..7
    const int wr = w >> 2, wc = w & 3;     // wave grid 2x4
    const int ra = lane & 15, kg = lane >> 4;

    // staging mapping: thread -> (channel c, 16 consecutive k)
    const int c  = tid >> 2;               // 0..127
    const int ks = (tid & 3) << 4;         // 0,16,32,48
    const float* gq = x + (size_t)n * CN * SN + (size_t)c * SN + bx * GSL;

    f32x4 acc[4][2];
#pragma unroll
    for (int a = 0; a < 4; ++a)
#pragma unroll
        for (int b = 0; b < 2; ++b) acc[a][b] = (f32x4){0.f, 0.f, 0.f, 0.f};

    float4 st[4];
    auto load_chunk = [&](int t) {
        const float4* p = reinterpret_cast<const float4*>(gq + t * 64 + ks);
        st[0] = p[0]; st[1] = p[1]; st[2] = p[2]; st[3] = p[3];
    };

    auto stage = [&](int buf) {
        u16x8 ha, hb, la, lb;
        unsigned int p;
#define CV8(hv, lv, i, val) { p = splitpack(val); hv[i] = (unsigned short)(p & 0xffffu); lv[i] = (unsigned short)(p >> 16); }
        CV8(ha, la, 0, st[0].x) CV8(ha, la, 1, st[0].y) CV8(ha, la, 2, st[0].z) CV8(ha, la, 3, st[0].w)
        CV8(ha, la, 4, st[1].x) CV8(ha, la, 5, st[1].y) CV8(ha, la, 6, st[1].z) CV8(ha, la, 7, st[1].w)
        CV8(hb, lb, 0, st[2].x) CV8(hb, lb, 1, st[2].y) CV8(hb, lb, 2, st[2].z) CV8(hb, lb, 3, st[2].w)
        CV8(hb, lb, 4, st[3].x) CV8(hb, lb, 5, st[3].y) CV8(hb, lb, 6, st[3].z) CV8(hb, lb, 7, st[3].w)
#undef CV8
        char* ph = reinterpret_cast<char*>(lh[buf]) + c * 128;
        char* pl = reinterpret_cast<char*>(ll[buf]) + c * 128;
        const int sw = (c & 7) << 4;
        const int k2 = ks * 2;
        *reinterpret_cast<u16x8*>(ph + (k2 ^ sw))        = ha;
        *reinterpret_cast<u16x8*>(ph + ((k2 + 16) ^ sw)) = hb;
        *reinterpret_cast<u16x8*>(pl + (k2 ^ sw))        = la;
        *reinterpret_cast<u16x8*>(pl + ((k2 + 16) ^ sw)) = lb;
    };

    auto compute = [&](int buf) {
        const unsigned short* LH = lh[buf];
        const unsigned short* LL = ll[buf];
#pragma unroll
        for (int kk = 0; kk < 2; ++kk) {
            const int kb = kk * 64 + (kg << 4);
            bf16x8 ah[4], al[4], bh[2], bl[2];
#pragma unroll
            for (int it = 0; it < 4; ++it) {
                const int row = wr * 64 + it * 16 + ra;
                ah[it] = ldsfrag(LH, row, kb, 128);
                al[it] = ldsfrag(LL, row, kb, 128);
            }
#pragma unroll
            for (int jt = 0; jt < 2; ++jt) {
                const int row = wc * 32 + jt * 16 + ra;
                bh[jt] = ldsfrag(LH, row, kb, 128);
                bl[jt] = ldsfrag(LL, row, kb, 128);
            }
#pragma unroll
            for (int it = 0; it < 4; ++it)
#pragma unroll
                for (int jt = 0; jt < 2; ++jt) {
                    acc[it][jt] = mm(ah[it], bh[jt], acc[it][jt]);
                    acc[it][jt] = mm(ah[it], bl[jt], acc[it][jt]);
                    acc[it][jt] = mm(al[it], bh[jt], acc[it][jt]);
                }
        }
    };

    load_chunk(0);
    for (int t = 0; t < GCH; ++t) {
        stage(t & 1);
        if (t < GCH - 1) load_chunk(t + 1);   // prefetch overlaps MFMA
        __syncthreads();                      // single barrier per chunk (dbuf)
        compute(t & 1);
    }

    // epilogue: C/D map row=(lane>>4)*4+q, col=lane&15
    const int q4 = kg << 2;
    if (!ATOMIC) {
        float* P = dst + (size_t)(n * GB + bx) * (CN * CN);
#pragma unroll
        for (int it = 0; it < 4; ++it)
#pragma unroll
            for (int jt = 0; jt < 2; ++jt)
#pragma unroll
                for (int q = 0; q < 4; ++q)
                    P[(wr * 64 + it * 16 + q4 + q) * CN + wc * 32 + jt * 16 + ra] = acc[it][jt][q];
    } else {
        float* E = dst + (size_t)n * CN * CN;
#pragma unroll
        for (int it = 0; it < 4; ++it)
#pragma unroll
            for (int jt = 0; jt < 2; ++jt)
#pragma unroll
                for (int q = 0; q < 4; ++q)
                    atomicAdd(&E[(wr * 64 + it * 16 + q4 + q) * CN + wc * 32 + jt * 16 + ra], acc[it][jt][q]);
    }
}

// ---------------- K2: fused reduce + softmin -> bf16-hi attention ----------------
// grid (CN, NB), block 64 (one wave per row). Deterministic fixed-order k sum.
template <bool REDUCE>
__global__ void finish_kernel(const float* __restrict__ src,
                              unsigned short* __restrict__ att_h) {
    const int i = blockIdx.x, n = blockIdx.y, l = threadIdx.x;
    float e0, e1;
    if (REDUCE) {
        const float* p = src + (size_t)n * GB * (CN * CN) + i * CN;
        e0 = 0.f; e1 = 0.f;
#pragma unroll 8
        for (int k = 0; k < GB; ++k) {
            e0 += p[(size_t)k * (CN * CN) + l];
            e1 += p[(size_t)k * (CN * CN) + l + 64];
        }
    } else {
        const float* E = src + ((size_t)n * CN + i) * CN;
        e0 = E[l]; e1 = E[l + 64];
    }
    float m = fminf(e0, e1);
#pragma unroll
    for (int off = 32; off > 0; off >>= 1) m = fminf(m, __shfl_xor(m, off));
    const float p0 = expf(m - e0);
    const float p1 = expf(m - e1);
    float s = p0 + p1;
#pragma unroll
    for (int off = 32; off > 0; off >>= 1) s += __shfl_xor(s, off);
    const float inv = 1.f / s;
    const size_t o = ((size_t)n * CN + i) * CN;
    att_h[o + l]      = f2bh(p0 * inv);
    att_h[o + l + 64] = f2bh(p1 * inv);
}

// ---------------- K3: out = attn @ Q via MFMA, double-buffered ----------------
// grid (PB, NB), block 512. Per block: 256 s (4 chunks of 64).
// A = attn-hi in registers. B = q-hi only. x loads NORMAL (L3-resident after
// gram), out stores NT (A/B test: does nt bypass Infinity-Cache allocation?).
// LDS: 2 x [64 s][128 j] bf16 hi, pitch 256B, XOR-swizzled.  32 KB.
__global__ __launch_bounds__(512, 4) void pv_mfma(const float* __restrict__ x,
                                                  const unsigned short* __restrict__ att_h,
                                                  float* __restrict__ out) {
    __shared__ __align__(16) unsigned short qh[2][64 * CN];
    const int bx = blockIdx.x, n = blockIdx.y;
    const int tid = threadIdx.x;
    const int lane = tid & 63;
    const int w = tid >> 6;                 // wave -> i-tile (rows w*16..w*16+15)
    const int ra = lane & 15, kg = lane >> 4;

    // A-fragments from global (attn L2-resident across blocks)
    bf16x8 a_h[4];
    {
        const size_t rowoff = ((size_t)n * CN + w * 16 + ra) * CN + kg * 8;
        const unsigned short* Ah = att_h + rowoff;
#pragma unroll
        for (int kk = 0; kk < 4; ++kk)
            a_h[kk] = *reinterpret_cast<const bf16x8*>(Ah + kk * 32);
    }

    // staging mapping: thread -> 4x4 micro-block (j0..j0+3, s0..s0+3)
    const int j0 = (tid >> 4) * 4;          // 0..124
    const int s0 = (tid & 15) * 4;          // 0..60
    const float* gx = x + (size_t)n * CN * SN;
    const int sbase = bx * (PCH * 64);

    f32x4 st[4];
    auto load_chunk = [&](int sb) {
#pragma unroll
        for (int r = 0; r < 4; ++r)
            st[r] = *reinterpret_cast<const f32x4*>(gx + (size_t)(j0 + r) * SN + sb + s0);
    };

    auto stage = [&](int buf) {
        char* base = reinterpret_cast<char*>(qh[buf]);
#pragma unroll
        for (int r = 0; r < 4; ++r) {       // r = local s offset (compile-time)
            u16x4 hv;
            hv[0] = f2bh(st[0][r]);
            hv[1] = f2bh(st[1][r]);
            hv[2] = f2bh(st[2][r]);
            hv[3] = f2bh(st[3][r]);
            const int s = s0 + r;
            const int off = s * 256 + ((j0 * 2) ^ ((s & 7) << 4));
            *reinterpret_cast<u16x4*>(base + off) = hv;
        }
    };

    auto compute = [&](int buf, int sb) {
        const unsigned short* Q = qh[buf];
#pragma unroll
        for (int stile = 0; stile < 4; ++stile) {
            f32x4 acc = (f32x4){0.f, 0.f, 0.f, 0.f};
            const int srow = stile * 16 + ra;
#pragma unroll
            for (int kk = 0; kk < 4; ++kk) {
                const int kb = kk * 64 + (kg << 4);
                bf16x8 bh = ldsfrag(Q, srow, kb, 256);
                acc = mm(a_h[kk], bh, acc);
            }
            float* o = out + ((size_t)n * CN + w * 16 + (kg << 2)) * SN + sb + stile * 16 + ra;
#pragma unroll
            for (int q = 0; q < 4; ++q)
                __builtin_nontemporal_store(acc[q], o + (size_t)q * SN);
        }
    };

    load_chunk(sbase);
    for (int t = 0; t < PCH; ++t) {
        stage(t & 1);
        if (t < PCH - 1) load_chunk(sbase + (t + 1) * 64);
        __syncthreads();
        compute(t & 1, sbase + t * 64);
    }
}

extern "C" void kernel_launch(void* const* d_in, const int* in_sizes, int n_in,
                              void* d_out, int out_size, void* d_ws, size_t ws_size,
                              hipStream_t stream) {
    (void)in_sizes; (void)n_in; (void)out_size;
    const float* x = (const float*)d_in[0];
    float* out = (float*)d_out;

    // ws: [energy 256KB][att_h 128KB][partials 16.8MB]
    float* energy = (float*)d_ws;
    unsigned short* att_h = (unsigned short*)(energy + (size_t)NB * CN * CN);
    float* part = (float*)(att_h + (size_t)NB * CN * CN);
    const size_t need =
        (size_t)NB * CN * CN * sizeof(float) +
        (size_t)NB * CN * CN * sizeof(unsigned short) +
        (size_t)NB * GB * CN * CN * sizeof(float);

    if (ws_size >= need) {
        gram_mfma<false><<<dim3(GB, NB), 512, 0, stream>>>(x, part);
        finish_kernel<true><<<dim3(CN, NB), 64, 0, stream>>>(part, att_h);
    } else {
        hipMemsetAsync(energy, 0, (size_t)NB * CN * CN * sizeof(float), stream);
        gram_mfma<true><<<dim3(GB, NB), 512, 0, stream>>>(x, energy);
        finish_kernel<false><<<dim3(CN, NB), 64, 0, stream>>>(energy, att_h);
    }
    pv_mfma<<<dim3(PB, NB), 512, 0, stream>>>(x, att_h, out);
}